// Round 4
// baseline (370.698 us; speedup 1.0000x reference)
//
#include <hip/hip_runtime.h>
#include <math.h>

// Sizes (fixed by the problem)
#define B_SZ 8
#define L_SZ 4096
#define D_SZ 1024
#define M_SZ 64
#define ROWS (B_SZ * L_SZ)   // 32768
#define NCHUNK 64            // L / CHUNK
#define CHUNK 64

#define FMA4(acc, sc, v) { (acc).x += (sc)*(v).x; (acc).y += (sc)*(v).y; (acc).z += (sc)*(v).z; (acc).w += (sc)*(v).w; }
#define SCALE4(v, sc) { (v).x *= (sc); (v).y *= (sc); (v).z *= (sc); (v).w *= (sc); }

typedef __attribute__((ext_vector_type(8))) short bf16x8;
typedef __attribute__((ext_vector_type(4))) float f32x4;

__device__ __forceinline__ float sigmoid_f(float z) { return 1.0f / (1.0f + __expf(-z)); }
__device__ __forceinline__ float decay_of(const float* __restrict__ dp) {
  return 0.9f + (0.999f - 0.9f) * sigmoid_f(dp[0]);
}
// fp32 -> bf16 round-to-nearest-even
__device__ __forceinline__ unsigned short f2bf(float f) {
  unsigned int u = __float_as_uint(f);
  unsigned int r = (u + 0x7FFFu + ((u >> 16) & 1u)) >> 16;
  return (unsigned short)r;
}

// async global->LDS, 16B per lane. HW: wave-uniform LDS base + lane*16;
// per-lane GLOBAL source. All call sites keep (sub-)waves fully active.
__device__ __forceinline__ void gl2lds16(const void* g, void* l) {
  __builtin_amdgcn_global_load_lds(
      (const __attribute__((address_space(1))) unsigned int*)g,
      (__attribute__((address_space(3))) unsigned int*)l, 16, 0, 0);
}

// ---------------- Kernel 0: qkv weight prep ----------------
// Wt laid out EXACTLY in k1's staged order: [kt 0..15][n 0..207][chunk 0..8][8 bf16],
// each kt-slice padded to 1920 16B-chunks (30720B = 7.5*256) for full-wave staging.
// n: 0-63 Wq cols, 64-127 Wk, 128-191 Wv, 192 Wg, 193-207 zero. chunk 8 = row pad.
#define BT_CH     1872
#define BT_CH_PAD 1920
#define BT_BYTES  (BT_CH_PAD * 16)
__global__ __launch_bounds__(256) void k0_prep(
    const float* __restrict__ Wq, const float* __restrict__ Wk,
    const float* __restrict__ Wv, const float* __restrict__ Wg,
    unsigned short* __restrict__ Wt)
{
  const int n = blockIdx.x;      // 0..207
  #pragma unroll
  for (int j = 0; j < 5; ++j) {
    int idx = threadIdx.x + 256 * j;   // 0..1151 : 16 kt * 72 shorts
    if (idx < 1152) {
      int kt = idx / 72;
      int r  = idx - kt * 72;
      int c = r >> 3, e = r & 7;
      float v = 0.f;
      if (c < 8 && n < 193) {
        int k = kt * 64 + c * 8 + e;
        v = (n < 64)  ? Wq[(size_t)k * 64 + n]
          : (n < 128) ? Wk[(size_t)k * 64 + (n - 64)]
          : (n < 192) ? Wv[(size_t)k * 64 + (n - 128)]
                      : Wg[k];
      }
      Wt[((size_t)kt * BT_CH_PAD + (size_t)n * 9 + c) * 8 + e] = f2bf(v);
    }
  }
}

// ---------------- Kernel 0b: Wo prep (transpose + hi/lo bf16 split) ----------------
// woth/wotl: [n 0..1023][k 0..71] bf16, rows padded to 72 (144B) -> k5 stages them
// as LINEAR chunks and reads frags conflict-free. Wo = hi + lo to fp32 accuracy.
__global__ __launch_bounds__(256) void k0b_wo(
    const float* __restrict__ Wo, unsigned short* __restrict__ woth,
    unsigned short* __restrict__ wotl)
{
  const int n = blockIdx.x * 256 + threadIdx.x;   // 0..1023
  unsigned int hp[36], lp[36];
  #pragma unroll
  for (int kp = 0; kp < 32; ++kp) {
    float v0 = Wo[(size_t)(2 * kp) * D_SZ + n];
    float v1 = Wo[(size_t)(2 * kp + 1) * D_SZ + n];
    unsigned short h0 = f2bf(v0), h1 = f2bf(v1);
    unsigned short l0 = f2bf(v0 - __uint_as_float((unsigned)h0 << 16));
    unsigned short l1 = f2bf(v1 - __uint_as_float((unsigned)h1 << 16));
    hp[kp] = (unsigned)h0 | ((unsigned)h1 << 16);
    lp[kp] = (unsigned)l0 | ((unsigned)l1 << 16);
  }
  #pragma unroll
  for (int kp = 32; kp < 36; ++kp) { hp[kp] = 0; lp[kp] = 0; }
  #pragma unroll
  for (int j = 0; j < 9; ++j) {
    uint4 uh = make_uint4(hp[4*j], hp[4*j+1], hp[4*j+2], hp[4*j+3]);
    uint4 ul = make_uint4(lp[4*j], lp[4*j+1], lp[4*j+2], lp[4*j+3]);
    *reinterpret_cast<uint4*>(&woth[(size_t)n * 72 + 8 * j]) = uh;
    *reinterpret_cast<uint4*>(&wotl[(size_t)n * 72 + 8 * j]) = ul;
  }
}

// ---------------- Kernel 1: MFMA fused q,k,v,gate projection ----------------
#define K1_ROWS 64
#define A_STRIDE 272          // 64 fp32 + 16B pad
#define B_STRIDE 144          // 64 bf16 + 16B pad

__global__ __launch_bounds__(256, 3) void k1_qkvg_mfma(
    const float* __restrict__ x, const unsigned short* __restrict__ Wt,
    const float* __restrict__ bg,
    float* __restrict__ q_ws, float* __restrict__ a_ws, float* __restrict__ b_ws)
{
  __shared__ __align__(16) unsigned char AsB[K1_ROWS * A_STRIDE];   // 17408 B
  __shared__ __align__(16) unsigned char BsB[BT_BYTES];             // 30720 B

  const int tid  = threadIdx.x;
  const int lane = tid & 63;
  const int w    = tid >> 6;
  const int quad = lane >> 4;
  const int l15  = lane & 15;
  const int row0 = blockIdx.x * K1_ROWS;

  const unsigned char* xb  = (const unsigned char*)(x + (size_t)row0 * D_SZ);
  const unsigned char* wtb = (const unsigned char*)Wt;

  const unsigned char* xA[5];
  #pragma unroll
  for (int i = 0; i < 5; ++i) {
    int ci  = i * 256 + tid;
    int row = ci / 17;
    int c17 = ci - row * 17;
    xA[i] = xb + (size_t)row * 4096 + (c17 < 16 ? c17 * 16 : 0);
  }

  f32x4 acc[13];
  #pragma unroll
  for (int tn = 0; tn < 13; ++tn) acc[tn] = (f32x4){0.f, 0.f, 0.f, 0.f};

  for (int t = 0; t < 16; ++t) {
    #pragma unroll
    for (int i = 0; i < 4; ++i)
      gl2lds16(xA[i] + (size_t)t * 256, AsB + (i * 256 + tid) * 16);
    if (tid < 64)
      gl2lds16(xA[4] + (size_t)t * 256, AsB + (4 * 256 + tid) * 16);
    const unsigned char* wt_t = wtb + (size_t)t * BT_BYTES;
    #pragma unroll
    for (int i = 0; i < 7; ++i)
      gl2lds16(wt_t + (i * 256 + tid) * 16, BsB + (i * 256 + tid) * 16);
    if (tid < 128)
      gl2lds16(wt_t + (7 * 256 + tid) * 16, BsB + (7 * 256 + tid) * 16);

    __syncthreads();

    bf16x8 af[2];
    #pragma unroll
    for (int kt = 0; kt < 2; ++kt) {
      const unsigned char* ap = AsB + (16 * w + l15) * A_STRIDE + kt * 128 + quad * 32;
      float4 lo = *reinterpret_cast<const float4*>(ap);
      float4 hi = *reinterpret_cast<const float4*>(ap + 16);
      uint4 p;
      p.x = (unsigned)f2bf(lo.x) | ((unsigned)f2bf(lo.y) << 16);
      p.y = (unsigned)f2bf(lo.z) | ((unsigned)f2bf(lo.w) << 16);
      p.z = (unsigned)f2bf(hi.x) | ((unsigned)f2bf(hi.y) << 16);
      p.w = (unsigned)f2bf(hi.z) | ((unsigned)f2bf(hi.w) << 16);
      af[kt] = *reinterpret_cast<bf16x8*>(&p);
    }
    #pragma unroll
    for (int tn = 0; tn < 13; ++tn) {
      #pragma unroll
      for (int kt = 0; kt < 2; ++kt) {
        bf16x8 bf = *reinterpret_cast<const bf16x8*>(
            BsB + (tn * 16 + l15) * B_STRIDE + kt * 64 + quad * 16);
        acc[tn] = __builtin_amdgcn_mfma_f32_16x16x32_bf16(af[kt], bf, acc[tn], 0, 0, 0);
      }
    }
    __syncthreads();
  }

  const float bg0 = bg[0];
  float g4[4];
  #pragma unroll
  for (int r = 0; r < 4; ++r) {
    float gv = __shfl(acc[12][r], lane & 48);
    g4[r] = sigmoid_f(gv + bg0);
  }

  float (*T)[68] = (float(*)[68])AsB;   // 64*68*4 = 17408
  const int erow = tid >> 2, eq4 = tid & 3;
  #pragma unroll
  for (int p = 0; p < 3; ++p) {
    float* dst = (p == 0) ? q_ws : (p == 1) ? a_ws : b_ws;
    #pragma unroll
    for (int tn4 = 0; tn4 < 4; ++tn4) {
      #pragma unroll
      for (int r = 0; r < 4; ++r) {
        float v = acc[p * 4 + tn4][r];
        if (p > 0) v *= g4[r];
        T[16 * w + quad * 4 + r][tn4 * 16 + l15] = v;
      }
    }
    __syncthreads();
    float4 vv[4];
    #pragma unroll
    for (int j = 0; j < 4; ++j)
      vv[j] = *reinterpret_cast<float4*>(&T[erow][eq4 * 16 + 4 * j]);
    #pragma unroll
    for (int j = 0; j < 4; ++j)
      *reinterpret_cast<float4*>(&dst[(size_t)(row0 + erow) * 64 + eq4 * 16 + 4 * j]) = vv[j];
    if (p < 2) __syncthreads();
  }
}

// ---------------- Kernel 2: per-chunk state delta ----------------
__global__ __launch_bounds__(256) void k2_delta(
    const float* __restrict__ a_ws, const float* __restrict__ b_ws,
    const float* __restrict__ dp, float* __restrict__ dS)
{
  __shared__ float Aa[64][64];
  __shared__ float Bc[64][64];
  __shared__ float pw[64];
  const int tid = threadIdx.x;
  const int bc = blockIdx.x;
  const int rowbase = (bc >> 6) * L_SZ + (bc & 63) * CHUNK;
  const int s = tid >> 2, m0 = (tid & 3) * 16;
  #pragma unroll
  for (int j = 0; j < 4; ++j) {
    *reinterpret_cast<float4*>(&Aa[s][m0 + 4*j]) =
        *reinterpret_cast<const float4*>(&a_ws[(size_t)(rowbase + s) * 64 + m0 + 4*j]);
    *reinterpret_cast<float4*>(&Bc[s][m0 + 4*j]) =
        *reinterpret_cast<const float4*>(&b_ws[(size_t)(rowbase + s) * 64 + m0 + 4*j]);
  }
  if (tid < 64) pw[tid] = powf(decay_of(dp), (float)(63 - tid));
  __syncthreads();
  const int d0 = tid >> 2, e0 = (tid & 3) * 16;
  float4 o0 = make_float4(0,0,0,0), o1 = o0, o2 = o0, o3 = o0;
  for (int ss = 0; ss < 64; ++ss) {
    float wa = pw[ss] * Aa[ss][d0];
    float4 b0 = *reinterpret_cast<float4*>(&Bc[ss][e0+0]);
    float4 b1 = *reinterpret_cast<float4*>(&Bc[ss][e0+4]);
    float4 b2 = *reinterpret_cast<float4*>(&Bc[ss][e0+8]);
    float4 b3 = *reinterpret_cast<float4*>(&Bc[ss][e0+12]);
    FMA4(o0, wa, b0); FMA4(o1, wa, b1); FMA4(o2, wa, b2); FMA4(o3, wa, b3);
  }
  float* dst = &dS[((size_t)bc << 12) + d0 * 64 + e0];
  *reinterpret_cast<float4*>(dst + 0)  = o0;
  *reinterpret_cast<float4*>(dst + 4)  = o1;
  *reinterpret_cast<float4*>(dst + 8)  = o2;
  *reinterpret_cast<float4*>(dst + 12) = o3;
}

// ---------------- Kernel 3: elementwise scan over chunks ----------------
__global__ __launch_bounds__(256) void k3_scan(
    const float* __restrict__ dS, const float* __restrict__ dp,
    float* __restrict__ Sst, float* __restrict__ sfin)
{
  const int g = blockIdx.x * 256 + threadIdx.x;
  const int b = g >> 12;
  const int de = g & 4095;
  const float dC = powf(decay_of(dp), 64.0f);
  const size_t base = ((size_t)(b * 64) << 12) + de;
  float d[NCHUNK];
  #pragma unroll
  for (int c = 0; c < NCHUNK; ++c) d[c] = dS[base + ((size_t)c << 12)];
  float s = 0.f;
  #pragma unroll
  for (int c = 0; c < NCHUNK; ++c) {
    Sst[base + ((size_t)c << 12)] = s;
    s = dC * s + d[c];
  }
  sfin[((size_t)b << 12) + de] = s;
}

// ---------------- Kernel 4: intra-chunk outputs ----------------
__global__ __launch_bounds__(256) void k4_intra(
    const float* __restrict__ q_ws, const float* __restrict__ a_ws,
    const float* __restrict__ b_ws, const float* __restrict__ Sst,
    const float* __restrict__ dp, float* __restrict__ outs)
{
  __shared__ float Qs[64][68];
  __shared__ float Ps[64][68];
  __shared__ float Bs[64][64];
  __shared__ float S0s[64][64];
  __shared__ float pw[65];
  const int tid = threadIdx.x;
  const int bc = blockIdx.x;
  const int rowbase = (bc >> 6) * L_SZ + (bc & 63) * CHUNK;
  const int s = tid >> 2, m0 = (tid & 3) * 16;
  #pragma unroll
  for (int j = 0; j < 4; ++j) {
    float4 qv = *reinterpret_cast<const float4*>(&q_ws[(size_t)(rowbase + s) * 64 + m0 + 4*j]);
    Qs[s][m0+4*j+0] = qv.x; Qs[s][m0+4*j+1] = qv.y; Qs[s][m0+4*j+2] = qv.z; Qs[s][m0+4*j+3] = qv.w;
    float4 av = *reinterpret_cast<const float4*>(&a_ws[(size_t)(rowbase + s) * 64 + m0 + 4*j]);
    Ps[m0+4*j+0][s] = av.x; Ps[m0+4*j+1][s] = av.y; Ps[m0+4*j+2][s] = av.z; Ps[m0+4*j+3][s] = av.w;
    float4 bv = *reinterpret_cast<const float4*>(&b_ws[(size_t)(rowbase + s) * 64 + m0 + 4*j]);
    *reinterpret_cast<float4*>(&Bs[s][m0+4*j]) = bv;
    float4 sv = *reinterpret_cast<const float4*>(&Sst[((size_t)bc << 12) + tid*16 + 4*j]);
    *reinterpret_cast<float4*>(&(&S0s[0][0])[tid*16 + 4*j]) = sv;
  }
  if (tid < 65) pw[tid] = powf(decay_of(dp), (float)tid);
  __syncthreads();

  const int t0 = tid >> 2, c0 = (tid & 3) * 16;
  float4 r0 = make_float4(0,0,0,0), r1 = r0, r2 = r0, r3 = r0;
  for (int m = 0; m < 64; ++m) {
    float qv = Qs[t0][m];
    float4 a0 = *reinterpret_cast<float4*>(&Ps[m][c0+0]);
    float4 a1 = *reinterpret_cast<float4*>(&Ps[m][c0+4]);
    float4 a2 = *reinterpret_cast<float4*>(&Ps[m][c0+8]);
    float4 a3 = *reinterpret_cast<float4*>(&Ps[m][c0+12]);
    FMA4(r0, qv, a0); FMA4(r1, qv, a1); FMA4(r2, qv, a2); FMA4(r3, qv, a3);
  }
  float rr[16] = {r0.x,r0.y,r0.z,r0.w, r1.x,r1.y,r1.z,r1.w,
                  r2.x,r2.y,r2.z,r2.w, r3.x,r3.y,r3.z,r3.w};
  __syncthreads();
  #pragma unroll
  for (int j = 0; j < 16; ++j) {
    const int sidx = c0 + j;
    Ps[t0][sidx] = (sidx <= t0) ? rr[j] * pw[t0 - sidx] : 0.f;
  }
  __syncthreads();

  float4 o0 = make_float4(0,0,0,0), o1 = o0, o2 = o0, o3 = o0;
  for (int m = 0; m < 64; ++m) {
    float qv = Qs[t0][m];
    float4 v0 = *reinterpret_cast<float4*>(&S0s[m][c0+0]);
    float4 v1 = *reinterpret_cast<float4*>(&S0s[m][c0+4]);
    float4 v2 = *reinterpret_cast<float4*>(&S0s[m][c0+8]);
    float4 v3 = *reinterpret_cast<float4*>(&S0s[m][c0+12]);
    FMA4(o0, qv, v0); FMA4(o1, qv, v1); FMA4(o2, qv, v2); FMA4(o3, qv, v3);
  }
  const float dsc = pw[t0 + 1];
  SCALE4(o0, dsc); SCALE4(o1, dsc); SCALE4(o2, dsc); SCALE4(o3, dsc);
  for (int ss = 0; ss < 64; ++ss) {
    float pv = Ps[t0][ss];
    float4 b0 = *reinterpret_cast<float4*>(&Bs[ss][c0+0]);
    float4 b1 = *reinterpret_cast<float4*>(&Bs[ss][c0+4]);
    float4 b2 = *reinterpret_cast<float4*>(&Bs[ss][c0+8]);
    float4 b3 = *reinterpret_cast<float4*>(&Bs[ss][c0+12]);
    FMA4(o0, pv, b0); FMA4(o1, pv, b1); FMA4(o2, pv, b2); FMA4(o3, pv, b3);
  }
  float* dst = &outs[(size_t)(rowbase + t0) * 64 + c0];
  *reinterpret_cast<float4*>(dst + 0)  = o0;
  *reinterpret_cast<float4*>(dst + 4)  = o1;
  *reinterpret_cast<float4*>(dst + 8)  = o2;
  *reinterpret_cast<float4*>(dst + 12) = o3;
}

// ---------------- Kernel 5: output projection (MFMA, hi/lo split) ----------------
// y = outs @ Wo + bo via bf16 MFMA with error compensation:
//   o = oh + ol, Wo = wh + wl;  y ~= oh*wh + ol*wh + oh*wl  (ol*wl ~ 2^-16, dropped)
// Block: 64 rows x 128 cols; wave w -> rows 16w..16w+15 (8 col-frags).
// B staged linearly via global_load_lds from k0b's padded layout; epilogue
// transposes through LDS -> coalesced float4 stores (avoids R1's write amp).
#define K5_CB 128
__global__ __launch_bounds__(256, 2) void k5_mfma(
    const float* __restrict__ outs, const unsigned short* __restrict__ woth,
    const unsigned short* __restrict__ wotl, const float* __restrict__ bo,
    float* __restrict__ y)
{
  __shared__ __align__(16) unsigned char L[55296];  // Ah,Al 2*9216 + Bh,Bl 2*18432
  unsigned short* Ah = (unsigned short*)L;          // [64][72] bf16
  unsigned short* Al = Ah + 64 * 72;
  unsigned short* Bh = Al + 64 * 72;                // [128][72] bf16
  unsigned short* Bl = Bh + 128 * 72;
  float* T = (float*)L;                             // [64][132] fp32 (33792B), after MFMA

  const int tid  = threadIdx.x;
  const int lane = tid & 63;
  const int w    = tid >> 6;
  const int quad = lane >> 4;
  const int l15  = lane & 15;
  const int row0 = blockIdx.x * 64;
  const int n0   = blockIdx.y * K5_CB;

  // ---- stage B (hi/lo): two linear 18432B copies (1152 chunks each) ----
  const unsigned char* bsh = (const unsigned char*)(woth + (size_t)n0 * 72);
  const unsigned char* bsl = (const unsigned char*)(wotl + (size_t)n0 * 72);
  #pragma unroll
  for (int i = 0; i < 4; ++i) {
    gl2lds16(bsh + (i * 256 + tid) * 16, (unsigned char*)Bh + (i * 256 + tid) * 16);
    gl2lds16(bsl + (i * 256 + tid) * 16, (unsigned char*)Bl + (i * 256 + tid) * 16);
  }
  if (tid < 128) {
    gl2lds16(bsh + (1024 + tid) * 16, (unsigned char*)Bh + (1024 + tid) * 16);
    gl2lds16(bsl + (1024 + tid) * 16, (unsigned char*)Bl + (1024 + tid) * 16);
  }

  // ---- stage A: outs 64x64 fp32 -> hi/lo bf16 in LDS ----
  {
    const int ar = tid >> 2, kc = (tid & 3) * 16;
    float av[16];
    #pragma unroll
    for (int j = 0; j < 4; ++j) {
      float4 v = *reinterpret_cast<const float4*>(&outs[(size_t)(row0 + ar) * 64 + kc + 4 * j]);
      av[4*j+0] = v.x; av[4*j+1] = v.y; av[4*j+2] = v.z; av[4*j+3] = v.w;
    }
    unsigned int hp[8], lp[8];
    #pragma unroll
    for (int e = 0; e < 8; ++e) {
      unsigned short h0 = f2bf(av[2*e]), h1 = f2bf(av[2*e+1]);
      unsigned short l0 = f2bf(av[2*e]   - __uint_as_float((unsigned)h0 << 16));
      unsigned short l1 = f2bf(av[2*e+1] - __uint_as_float((unsigned)h1 << 16));
      hp[e] = (unsigned)h0 | ((unsigned)h1 << 16);
      lp[e] = (unsigned)l0 | ((unsigned)l1 << 16);
    }
    *reinterpret_cast<uint4*>(&Ah[ar*72 + kc])     = make_uint4(hp[0],hp[1],hp[2],hp[3]);
    *reinterpret_cast<uint4*>(&Ah[ar*72 + kc + 8]) = make_uint4(hp[4],hp[5],hp[6],hp[7]);
    *reinterpret_cast<uint4*>(&Al[ar*72 + kc])     = make_uint4(lp[0],lp[1],lp[2],lp[3]);
    *reinterpret_cast<uint4*>(&Al[ar*72 + kc + 8]) = make_uint4(lp[4],lp[5],lp[6],lp[7]);
  }
  __syncthreads();   // drains gl2lds (vmcnt) + ds_writes

  // ---- MFMA ----
  bf16x8 afh[2], afl[2];
  #pragma unroll
  for (int kt = 0; kt < 2; ++kt) {
    afh[kt] = *reinterpret_cast<bf16x8*>(&Ah[(16*w + l15)*72 + kt*32 + quad*8]);
    afl[kt] = *reinterpret_cast<bf16x8*>(&Al[(16*w + l15)*72 + kt*32 + quad*8]);
  }
  f32x4 acc[8];
  #pragma unroll
  for (int cf = 0; cf < 8; ++cf) acc[cf] = (f32x4){0.f, 0.f, 0.f, 0.f};
  #pragma unroll
  for (int cf = 0; cf < 8; ++cf) {
    bf16x8 bh0 = *reinterpret_cast<bf16x8*>(&Bh[(cf*16 + l15)*72 + quad*8]);
    bf16x8 bh1 = *reinterpret_cast<bf16x8*>(&Bh[(cf*16 + l15)*72 + 32 + quad*8]);
    bf16x8 bl0 = *reinterpret_cast<bf16x8*>(&Bl[(cf*16 + l15)*72 + quad*8]);
    bf16x8 bl1 = *reinterpret_cast<bf16x8*>(&Bl[(cf*16 + l15)*72 + 32 + quad*8]);
    acc[cf] = __builtin_amdgcn_mfma_f32_16x16x32_bf16(afh[0], bh0, acc[cf], 0, 0, 0);
    acc[cf] = __builtin_amdgcn_mfma_f32_16x16x32_bf16(afh[1], bh1, acc[cf], 0, 0, 0);
    acc[cf] = __builtin_amdgcn_mfma_f32_16x16x32_bf16(afl[0], bh0, acc[cf], 0, 0, 0);
    acc[cf] = __builtin_amdgcn_mfma_f32_16x16x32_bf16(afl[1], bh1, acc[cf], 0, 0, 0);
    acc[cf] = __builtin_amdgcn_mfma_f32_16x16x32_bf16(afh[0], bl0, acc[cf], 0, 0, 0);
    acc[cf] = __builtin_amdgcn_mfma_f32_16x16x32_bf16(afh[1], bl1, acc[cf], 0, 0, 0);
  }
  __syncthreads();   // A/B reads done; T may overwrite

  // ---- transpose through LDS ----
  #pragma unroll
  for (int cf = 0; cf < 8; ++cf)
    #pragma unroll
    for (int r = 0; r < 4; ++r)
      T[(16*w + quad*4 + r) * 132 + cf*16 + l15] = acc[cf][r];
  __syncthreads();

  // ---- bias + coalesced store ----
  const int er = tid >> 2, ec = (tid & 3) * 32;
  #pragma unroll
  for (int j = 0; j < 8; ++j) {
    float4 v = *reinterpret_cast<float4*>(&T[er*132 + ec + 4*j]);
    float4 b = *reinterpret_cast<const float4*>(&bo[n0 + ec + 4*j]);
    v.x += b.x; v.y += b.y; v.z += b.z; v.w += b.w;
    *reinterpret_cast<float4*>(&y[(size_t)(row0 + er) * D_SZ + n0 + ec + 4*j]) = v;
  }
}

// ---------------- Launcher ----------------
extern "C" void kernel_launch(void* const* d_in, const int* in_sizes, int n_in,
                              void* d_out, int out_size, void* d_ws, size_t ws_size,
                              hipStream_t stream) {
  (void)in_sizes; (void)n_in; (void)out_size; (void)ws_size;
  const float* x  = (const float*)d_in[0];
  const float* Wq = (const float*)d_in[1];
  const float* Wk = (const float*)d_in[2];
  const float* Wv = (const float*)d_in[3];
  const float* Wo = (const float*)d_in[4];
  const float* bo = (const float*)d_in[5];
  const float* Wg = (const float*)d_in[6];
  const float* bg = (const float*)d_in[7];
  const float* dp = (const float*)d_in[8];

  float* y    = (float*)d_out;                       // (8,4096,1024)
  float* sfin = y + (size_t)B_SZ * L_SZ * D_SZ;      // (8,64,64)

  float* ws   = (float*)d_ws;
  const size_t SEG = (size_t)ROWS * M_SZ;            // 2,097,152 floats
  float* q_ws = ws;
  float* a_ws = q_ws + SEG;
  float* b_ws = a_ws + SEG;
  float* dS   = b_ws + SEG;   // (B*NC, 64,64)
  float* Sst  = dS   + SEG;   // chunk-start states
  float* outs = Sst  + SEG;   // (32768, 64)
  // Wt (bf16, 16 slices x 30720B = 480KB) aliases the head of `outs`: dead
  // after k1 reads it, before k4 writes outs. Rewritten every call.
  unsigned short* Wt = (unsigned short*)outs;
  // Wo hi/lo transposed splits live after outs (2 x 144KB).
  unsigned short* woth = (unsigned short*)(outs + SEG);
  unsigned short* wotl = woth + (size_t)1024 * 72;

  k0_prep<<<dim3(208), dim3(256), 0, stream>>>(Wq, Wk, Wv, Wg, Wt);
  k0b_wo<<<dim3(4), dim3(256), 0, stream>>>(Wo, woth, wotl);
  k1_qkvg_mfma<<<dim3(ROWS / K1_ROWS), dim3(256), 0, stream>>>(x, Wt, bg, q_ws, a_ws, b_ws);
  k2_delta<<<dim3(B_SZ * NCHUNK), dim3(256), 0, stream>>>(a_ws, b_ws, dp, dS);
  k3_scan<<<dim3((B_SZ * M_SZ * M_SZ) / 256), dim3(256), 0, stream>>>(dS, dp, Sst, sfin);
  k4_intra<<<dim3(B_SZ * NCHUNK), dim3(256), 0, stream>>>(q_ws, a_ws, b_ws, Sst, dp, outs);
  k5_mfma<<<dim3(ROWS / 64, D_SZ / K5_CB), dim3(256), 0, stream>>>(outs, woth, wotl, bo, y);
}

// Round 5
// 352.294 us; speedup vs baseline: 1.0522x; 1.0522x over previous
//
#include <hip/hip_runtime.h>
#include <math.h>

// Sizes (fixed by the problem)
#define B_SZ 8
#define L_SZ 4096
#define D_SZ 1024
#define M_SZ 64
#define ROWS (B_SZ * L_SZ)   // 32768
#define NCHUNK 64            // L / CHUNK
#define CHUNK 64

#define FMA4(acc, sc, v) { (acc).x += (sc)*(v).x; (acc).y += (sc)*(v).y; (acc).z += (sc)*(v).z; (acc).w += (sc)*(v).w; }
#define SCALE4(v, sc) { (v).x *= (sc); (v).y *= (sc); (v).z *= (sc); (v).w *= (sc); }

typedef __attribute__((ext_vector_type(8))) short bf16x8;
typedef __attribute__((ext_vector_type(4))) float f32x4;

__device__ __forceinline__ float sigmoid_f(float z) { return 1.0f / (1.0f + __expf(-z)); }
__device__ __forceinline__ float decay_of(const float* __restrict__ dp) {
  return 0.9f + (0.999f - 0.9f) * sigmoid_f(dp[0]);
}
// fp32 -> bf16 round-to-nearest-even
__device__ __forceinline__ unsigned short f2bf(float f) {
  unsigned int u = __float_as_uint(f);
  unsigned int r = (u + 0x7FFFu + ((u >> 16) & 1u)) >> 16;
  return (unsigned short)r;
}

// async global->LDS, 16B per lane. HW: wave-uniform LDS base + lane*16;
// per-lane GLOBAL source. All call sites keep waves fully active.
__device__ __forceinline__ void gl2lds16(const void* g, void* l) {
  __builtin_amdgcn_global_load_lds(
      (const __attribute__((address_space(1))) unsigned int*)g,
      (__attribute__((address_space(3))) unsigned int*)l, 16, 0, 0);
}

// ---------------- Kernel 0: qkv weight prep ----------------
// Wt laid out EXACTLY in k1's staged order: [kt 0..15][n 0..207][chunk 0..8][8 bf16],
// each kt-slice padded to 2048 16B-chunks (32768B = 8*256) so k1's B-stage is
// exactly 8 chunks/thread in every wave (uniform vmcnt accounting).
// n: 0-63 Wq cols, 64-127 Wk, 128-191 Wv, 192 Wg, 193-207 zero. chunk 8 = row pad.
// Chunks 1872..2047 are dead pad (staged into an unread LDS region).
#define BT_CH_PAD 2048
#define BT_BYTES  (BT_CH_PAD * 16)
__global__ __launch_bounds__(256) void k0_prep(
    const float* __restrict__ Wq, const float* __restrict__ Wk,
    const float* __restrict__ Wv, const float* __restrict__ Wg,
    unsigned short* __restrict__ Wt)
{
  const int n = blockIdx.x;      // 0..207
  #pragma unroll
  for (int j = 0; j < 5; ++j) {
    int idx = threadIdx.x + 256 * j;   // 0..1151 : 16 kt * 72 shorts
    if (idx < 1152) {
      int kt = idx / 72;
      int r  = idx - kt * 72;
      int c = r >> 3, e = r & 7;
      float v = 0.f;
      if (c < 8 && n < 193) {
        int k = kt * 64 + c * 8 + e;
        v = (n < 64)  ? Wq[(size_t)k * 64 + n]
          : (n < 128) ? Wk[(size_t)k * 64 + (n - 64)]
          : (n < 192) ? Wv[(size_t)k * 64 + (n - 128)]
                      : Wg[k];
      }
      Wt[((size_t)kt * BT_CH_PAD + (size_t)n * 9 + c) * 8 + e] = f2bf(v);
    }
  }
}

// ---------------- Kernel 1: MFMA fused q,k,v,gate projection ----------------
// v4 (T3+T4 minimal): 64-row blocks, grid 512, 2 blocks/CU (64KB LDS).
//  - A (x, HBM) double-buffered 2x16KB, staged one k-tile AHEAD; waited with
//    counted s_waitcnt vmcnt(4) -> A loads stay in flight across the barrier.
//  - A rows unpadded (256B) with XOR swizzle byte^=(row&7)<<4 applied to the
//    GLOBAL source (inverse) and the LDS frag read (rule #21) -> 2-way banks.
//  - B (weights, L2-resident) single 32KB buffer, staged+waited same iter.
//  - Raw s_barrier + explicit lgkmcnt(0)/sched_barrier fences (rule #18).
//  - Gate = 13th N-tile; epilogue LDS-transpose -> coalesced float4 stores.
#define K1_ROWS 64
#define B_STRIDE 144          // 64 bf16 + 16B pad

__global__ __launch_bounds__(256, 2) void k1_qkvg_mfma(
    const float* __restrict__ x, const unsigned short* __restrict__ Wt,
    const float* __restrict__ bg,
    float* __restrict__ q_ws, float* __restrict__ a_ws, float* __restrict__ b_ws)
{
  __shared__ __align__(16) unsigned char As[2][16384];   // 2 x 64 rows x 256B
  __shared__ __align__(16) unsigned char Bs[BT_BYTES];   // 32768 B

  const int tid  = threadIdx.x;
  const int lane = tid & 63;
  const int w    = tid >> 6;
  const int quad = lane >> 4;
  const int l15  = lane & 15;
  const int row0 = blockIdx.x * K1_ROWS;

  const unsigned char* xb  = (const unsigned char*)(x + (size_t)row0 * D_SZ);
  const unsigned char* wtb = (const unsigned char*)Wt;

  // Per-thread A staging: 4 chunks, XOR-swizzled global source.
  // chunk c = i*256+tid -> row = c>>4, c16 = c&15;
  // src col byte = (c16*16) ^ ((row&7)<<4)  (involution; 16B-aligned).
  const unsigned char* xAsrc[4];
  #pragma unroll
  for (int i = 0; i < 4; ++i) {
    int c   = i * 256 + tid;
    int row = c >> 4, c16 = c & 15;
    xAsrc[i] = xb + (size_t)row * 4096 + ((c16 * 16) ^ ((row & 7) << 4));
  }

  f32x4 acc[13];
  #pragma unroll
  for (int tn = 0; tn < 13; ++tn) acc[tn] = (f32x4){0.f, 0.f, 0.f, 0.f};

  const int arow = 16 * w + l15;
  const int sw   = (l15 & 7) << 4;

  // ---- staging helpers ----
  auto stageA = [&](int buf, int t) {
    #pragma unroll
    for (int i = 0; i < 4; ++i)
      gl2lds16(xAsrc[i] + (size_t)t * 256, As[buf] + (i * 256 + tid) * 16);
  };
  auto stageB = [&](int t) {
    const unsigned char* wt_t = wtb + (size_t)t * BT_BYTES;
    #pragma unroll
    for (int i = 0; i < 8; ++i)
      gl2lds16(wt_t + (i * 256 + tid) * 16, Bs + (i * 256 + tid) * 16);
  };
  auto compute = [&](int buf) {
    bf16x8 af[2];
    const unsigned char* ap = As[buf] + arow * 256;
    #pragma unroll
    for (int kt = 0; kt < 2; ++kt) {
      float4 lo = *reinterpret_cast<const float4*>(ap + ((kt * 128 + quad * 32) ^ sw));
      float4 hi = *reinterpret_cast<const float4*>(ap + ((kt * 128 + quad * 32 + 16) ^ sw));
      uint4 p;
      p.x = (unsigned)f2bf(lo.x) | ((unsigned)f2bf(lo.y) << 16);
      p.y = (unsigned)f2bf(lo.z) | ((unsigned)f2bf(lo.w) << 16);
      p.z = (unsigned)f2bf(hi.x) | ((unsigned)f2bf(hi.y) << 16);
      p.w = (unsigned)f2bf(hi.z) | ((unsigned)f2bf(hi.w) << 16);
      af[kt] = *reinterpret_cast<bf16x8*>(&p);
    }
    #pragma unroll
    for (int tn = 0; tn < 13; ++tn) {
      #pragma unroll
      for (int kt = 0; kt < 2; ++kt) {
        bf16x8 bf = *reinterpret_cast<const bf16x8*>(
            Bs + (tn * 16 + l15) * B_STRIDE + kt * 64 + quad * 16);
        acc[tn] = __builtin_amdgcn_mfma_f32_16x16x32_bf16(af[kt], bf, acc[tn], 0, 0, 0);
      }
    }
  };

  // ---- pipeline ----
  // Invariant at top of iter t: this wave's outstanding VMEM = [A(t): 4 ops].
  stageA(0, 0);
  for (int t = 0; t < 15; ++t) {
    const int cur = t & 1;
    stageB(t);                  // +8  -> [A(t)4, B(t)8]
    stageA(cur ^ 1, t + 1);     // +4  -> [A(t)4, B(t)8, A(t+1)4]
    asm volatile("s_waitcnt vmcnt(4)" ::: "memory");   // A(t),B(t) landed (mine)
    __builtin_amdgcn_sched_barrier(0);
    __builtin_amdgcn_s_barrier();                      // landed for ALL waves
    compute(cur);
    asm volatile("s_waitcnt lgkmcnt(0)" ::: "memory"); // my LDS reads complete
    __builtin_amdgcn_sched_barrier(0);
    __builtin_amdgcn_s_barrier();                      // safe to overwrite B / As[cur]
  }
  // t = 15 (no next A)
  stageB(15);
  asm volatile("s_waitcnt vmcnt(0)" ::: "memory");
  __builtin_amdgcn_sched_barrier(0);
  __builtin_amdgcn_s_barrier();
  compute(1);
  __syncthreads();   // full drain before T aliases As

  // ---- gate: col 192 lives at l15==0 lanes of acc[12]; broadcast per quad ----
  const float bg0 = bg[0];
  float g4[4];
  #pragma unroll
  for (int r = 0; r < 4; ++r) {
    float gv = __shfl(acc[12][r], lane & 48);
    g4[r] = sigmoid_f(gv + bg0);
  }

  // ---- epilogue: transpose via LDS, coalesced float4 stores ----
  float (*T)[68] = (float(*)[68])As;   // 64*68*4 = 17408 <= 32768
  const int erow = tid >> 2, eq4 = tid & 3;
  #pragma unroll
  for (int p = 0; p < 3; ++p) {
    float* dst = (p == 0) ? q_ws : (p == 1) ? a_ws : b_ws;
    #pragma unroll
    for (int tn4 = 0; tn4 < 4; ++tn4) {
      #pragma unroll
      for (int r = 0; r < 4; ++r) {
        float v = acc[p * 4 + tn4][r];
        if (p > 0) v *= g4[r];
        T[16 * w + quad * 4 + r][tn4 * 16 + l15] = v;
      }
    }
    __syncthreads();
    float4 vv[4];
    #pragma unroll
    for (int j = 0; j < 4; ++j)
      vv[j] = *reinterpret_cast<float4*>(&T[erow][eq4 * 16 + 4 * j]);
    #pragma unroll
    for (int j = 0; j < 4; ++j)
      *reinterpret_cast<float4*>(&dst[(size_t)(row0 + erow) * 64 + eq4 * 16 + 4 * j]) = vv[j];
    if (p < 2) __syncthreads();
  }
}

// ---------------- Kernel 2: per-chunk state delta ----------------
__global__ __launch_bounds__(256) void k2_delta(
    const float* __restrict__ a_ws, const float* __restrict__ b_ws,
    const float* __restrict__ dp, float* __restrict__ dS)
{
  __shared__ float Aa[64][64];
  __shared__ float Bc[64][64];
  __shared__ float pw[64];
  const int tid = threadIdx.x;
  const int bc = blockIdx.x;
  const int rowbase = (bc >> 6) * L_SZ + (bc & 63) * CHUNK;
  const int s = tid >> 2, m0 = (tid & 3) * 16;
  #pragma unroll
  for (int j = 0; j < 4; ++j) {
    *reinterpret_cast<float4*>(&Aa[s][m0 + 4*j]) =
        *reinterpret_cast<const float4*>(&a_ws[(size_t)(rowbase + s) * 64 + m0 + 4*j]);
    *reinterpret_cast<float4*>(&Bc[s][m0 + 4*j]) =
        *reinterpret_cast<const float4*>(&b_ws[(size_t)(rowbase + s) * 64 + m0 + 4*j]);
  }
  if (tid < 64) pw[tid] = powf(decay_of(dp), (float)(63 - tid));
  __syncthreads();
  const int d0 = tid >> 2, e0 = (tid & 3) * 16;
  float4 o0 = make_float4(0,0,0,0), o1 = o0, o2 = o0, o3 = o0;
  for (int ss = 0; ss < 64; ++ss) {
    float wa = pw[ss] * Aa[ss][d0];
    float4 b0 = *reinterpret_cast<float4*>(&Bc[ss][e0+0]);
    float4 b1 = *reinterpret_cast<float4*>(&Bc[ss][e0+4]);
    float4 b2 = *reinterpret_cast<float4*>(&Bc[ss][e0+8]);
    float4 b3 = *reinterpret_cast<float4*>(&Bc[ss][e0+12]);
    FMA4(o0, wa, b0); FMA4(o1, wa, b1); FMA4(o2, wa, b2); FMA4(o3, wa, b3);
  }
  float* dst = &dS[((size_t)bc << 12) + d0 * 64 + e0];
  *reinterpret_cast<float4*>(dst + 0)  = o0;
  *reinterpret_cast<float4*>(dst + 4)  = o1;
  *reinterpret_cast<float4*>(dst + 8)  = o2;
  *reinterpret_cast<float4*>(dst + 12) = o3;
}

// ---------------- Kernel 3: elementwise scan over chunks ----------------
__global__ __launch_bounds__(256) void k3_scan(
    const float* __restrict__ dS, const float* __restrict__ dp,
    float* __restrict__ Sst, float* __restrict__ sfin)
{
  const int g = blockIdx.x * 256 + threadIdx.x;
  const int b = g >> 12;
  const int de = g & 4095;
  const float dC = powf(decay_of(dp), 64.0f);
  const size_t base = ((size_t)(b * 64) << 12) + de;
  float d[NCHUNK];
  #pragma unroll
  for (int c = 0; c < NCHUNK; ++c) d[c] = dS[base + ((size_t)c << 12)];
  float s = 0.f;
  #pragma unroll
  for (int c = 0; c < NCHUNK; ++c) {
    Sst[base + ((size_t)c << 12)] = s;
    s = dC * s + d[c];
  }
  sfin[((size_t)b << 12) + de] = s;
}

// ---------------- Kernel 4: intra-chunk outputs ----------------
__global__ __launch_bounds__(256) void k4_intra(
    const float* __restrict__ q_ws, const float* __restrict__ a_ws,
    const float* __restrict__ b_ws, const float* __restrict__ Sst,
    const float* __restrict__ dp, float* __restrict__ outs)
{
  __shared__ float Qs[64][68];
  __shared__ float Ps[64][68];
  __shared__ float Bs[64][64];
  __shared__ float S0s[64][64];
  __shared__ float pw[65];
  const int tid = threadIdx.x;
  const int bc = blockIdx.x;
  const int rowbase = (bc >> 6) * L_SZ + (bc & 63) * CHUNK;
  const int s = tid >> 2, m0 = (tid & 3) * 16;
  #pragma unroll
  for (int j = 0; j < 4; ++j) {
    float4 qv = *reinterpret_cast<const float4*>(&q_ws[(size_t)(rowbase + s) * 64 + m0 + 4*j]);
    Qs[s][m0+4*j+0] = qv.x; Qs[s][m0+4*j+1] = qv.y; Qs[s][m0+4*j+2] = qv.z; Qs[s][m0+4*j+3] = qv.w;
    float4 av = *reinterpret_cast<const float4*>(&a_ws[(size_t)(rowbase + s) * 64 + m0 + 4*j]);
    Ps[m0+4*j+0][s] = av.x; Ps[m0+4*j+1][s] = av.y; Ps[m0+4*j+2][s] = av.z; Ps[m0+4*j+3][s] = av.w;
    float4 bv = *reinterpret_cast<const float4*>(&b_ws[(size_t)(rowbase + s) * 64 + m0 + 4*j]);
    *reinterpret_cast<float4*>(&Bs[s][m0+4*j]) = bv;
    float4 sv = *reinterpret_cast<const float4*>(&Sst[((size_t)bc << 12) + tid*16 + 4*j]);
    *reinterpret_cast<float4*>(&(&S0s[0][0])[tid*16 + 4*j]) = sv;
  }
  if (tid < 65) pw[tid] = powf(decay_of(dp), (float)tid);
  __syncthreads();

  const int t0 = tid >> 2, c0 = (tid & 3) * 16;
  float4 r0 = make_float4(0,0,0,0), r1 = r0, r2 = r0, r3 = r0;
  for (int m = 0; m < 64; ++m) {
    float qv = Qs[t0][m];
    float4 a0 = *reinterpret_cast<float4*>(&Ps[m][c0+0]);
    float4 a1 = *reinterpret_cast<float4*>(&Ps[m][c0+4]);
    float4 a2 = *reinterpret_cast<float4*>(&Ps[m][c0+8]);
    float4 a3 = *reinterpret_cast<float4*>(&Ps[m][c0+12]);
    FMA4(r0, qv, a0); FMA4(r1, qv, a1); FMA4(r2, qv, a2); FMA4(r3, qv, a3);
  }
  float rr[16] = {r0.x,r0.y,r0.z,r0.w, r1.x,r1.y,r1.z,r1.w,
                  r2.x,r2.y,r2.z,r2.w, r3.x,r3.y,r3.z,r3.w};
  __syncthreads();
  #pragma unroll
  for (int j = 0; j < 16; ++j) {
    const int sidx = c0 + j;
    Ps[t0][sidx] = (sidx <= t0) ? rr[j] * pw[t0 - sidx] : 0.f;
  }
  __syncthreads();

  float4 o0 = make_float4(0,0,0,0), o1 = o0, o2 = o0, o3 = o0;
  for (int m = 0; m < 64; ++m) {
    float qv = Qs[t0][m];
    float4 v0 = *reinterpret_cast<float4*>(&S0s[m][c0+0]);
    float4 v1 = *reinterpret_cast<float4*>(&S0s[m][c0+4]);
    float4 v2 = *reinterpret_cast<float4*>(&S0s[m][c0+8]);
    float4 v3 = *reinterpret_cast<float4*>(&S0s[m][c0+12]);
    FMA4(o0, qv, v0); FMA4(o1, qv, v1); FMA4(o2, qv, v2); FMA4(o3, qv, v3);
  }
  const float dsc = pw[t0 + 1];
  SCALE4(o0, dsc); SCALE4(o1, dsc); SCALE4(o2, dsc); SCALE4(o3, dsc);
  for (int ss = 0; ss < 64; ++ss) {
    float pv = Ps[t0][ss];
    float4 b0 = *reinterpret_cast<float4*>(&Bs[ss][c0+0]);
    float4 b1 = *reinterpret_cast<float4*>(&Bs[ss][c0+4]);
    float4 b2 = *reinterpret_cast<float4*>(&Bs[ss][c0+8]);
    float4 b3 = *reinterpret_cast<float4*>(&Bs[ss][c0+12]);
    FMA4(o0, pv, b0); FMA4(o1, pv, b1); FMA4(o2, pv, b2); FMA4(o3, pv, b3);
  }
  float* dst = &outs[(size_t)(rowbase + t0) * 64 + c0];
  *reinterpret_cast<float4*>(dst + 0)  = o0;
  *reinterpret_cast<float4*>(dst + 4)  = o1;
  *reinterpret_cast<float4*>(dst + 8)  = o2;
  *reinterpret_cast<float4*>(dst + 12) = o3;
}

// ---------------- Kernel 5: output projection (scalar, R3 form) ----------------
// Os stride 65 (== 1 mod 32) de-aliases the scalar a-reads.
__global__ __launch_bounds__(256) void k5_proj(
    const float* __restrict__ outs, const float* __restrict__ Wo,
    const float* __restrict__ bo, float* __restrict__ y)
{
  __shared__ float Os[64][65];
  __shared__ float Ws[64][64];
  const int tid = threadIdx.x;
  const int tx = tid & 15, ty = tid >> 4;
  const int row0 = blockIdx.x * 64;
  const int n0 = blockIdx.y * 64;
  const int s = tid >> 2, m0 = (tid & 3) * 16;
  #pragma unroll
  for (int j = 0; j < 4; ++j) {
    float4 ov = *reinterpret_cast<const float4*>(&outs[(size_t)(row0 + s) * 64 + m0 + 4*j]);
    Os[s][m0+4*j+0] = ov.x; Os[s][m0+4*j+1] = ov.y; Os[s][m0+4*j+2] = ov.z; Os[s][m0+4*j+3] = ov.w;
    float4 wv = *reinterpret_cast<const float4*>(&Wo[(size_t)s * D_SZ + n0 + m0 + 4*j]);
    *reinterpret_cast<float4*>(&Ws[s][m0+4*j]) = wv;
  }
  __syncthreads();
  float4 acc[4];
  #pragma unroll
  for (int r = 0; r < 4; ++r) acc[r] = make_float4(0,0,0,0);
  for (int kk = 0; kk < 64; ++kk) {
    float a0 = Os[4*ty+0][kk];
    float a1 = Os[4*ty+1][kk];
    float a2 = Os[4*ty+2][kk];
    float a3 = Os[4*ty+3][kk];
    float4 w = *reinterpret_cast<float4*>(&Ws[kk][4*tx]);
    FMA4(acc[0], a0, w); FMA4(acc[1], a1, w); FMA4(acc[2], a2, w); FMA4(acc[3], a3, w);
  }
  float4 bv = *reinterpret_cast<const float4*>(&bo[n0 + 4*tx]);
  #pragma unroll
  for (int r = 0; r < 4; ++r) {
    float4 res;
    res.x = acc[r].x + bv.x; res.y = acc[r].y + bv.y;
    res.z = acc[r].z + bv.z; res.w = acc[r].w + bv.w;
    *reinterpret_cast<float4*>(&y[(size_t)(row0 + 4*ty + r) * D_SZ + n0 + 4*tx]) = res;
  }
}

// ---------------- Launcher ----------------
extern "C" void kernel_launch(void* const* d_in, const int* in_sizes, int n_in,
                              void* d_out, int out_size, void* d_ws, size_t ws_size,
                              hipStream_t stream) {
  (void)in_sizes; (void)n_in; (void)out_size; (void)ws_size;
  const float* x  = (const float*)d_in[0];
  const float* Wq = (const float*)d_in[1];
  const float* Wk = (const float*)d_in[2];
  const float* Wv = (const float*)d_in[3];
  const float* Wo = (const float*)d_in[4];
  const float* bo = (const float*)d_in[5];
  const float* Wg = (const float*)d_in[6];
  const float* bg = (const float*)d_in[7];
  const float* dp = (const float*)d_in[8];

  float* y    = (float*)d_out;                       // (8,4096,1024)
  float* sfin = y + (size_t)B_SZ * L_SZ * D_SZ;      // (8,64,64)

  float* ws   = (float*)d_ws;
  const size_t SEG = (size_t)ROWS * M_SZ;            // 2,097,152 floats
  float* q_ws = ws;
  float* a_ws = q_ws + SEG;
  float* b_ws = a_ws + SEG;
  float* dS   = b_ws + SEG;   // (B*NC, 64,64)
  float* Sst  = dS   + SEG;   // chunk-start states
  float* outs = Sst  + SEG;   // (32768, 64)
  // Wt (bf16, 16 slices x 32768B = 512KB) aliases the head of `outs`: dead
  // after k1 reads it, before k4 writes outs. Rewritten every call.
  unsigned short* Wt = (unsigned short*)outs;

  k0_prep<<<dim3(208), dim3(256), 0, stream>>>(Wq, Wk, Wv, Wg, Wt);
  k1_qkvg_mfma<<<dim3(ROWS / K1_ROWS), dim3(256), 0, stream>>>(x, Wt, bg, q_ws, a_ws, b_ws);
  k2_delta<<<dim3(B_SZ * NCHUNK), dim3(256), 0, stream>>>(a_ws, b_ws, dp, dS);
  k3_scan<<<dim3((B_SZ * M_SZ * M_SZ) / 256), dim3(256), 0, stream>>>(dS, dp, Sst, sfin);
  k4_intra<<<dim3(B_SZ * NCHUNK), dim3(256), 0, stream>>>(q_ws, a_ws, b_ws, Sst, dp, outs);
  k5_proj<<<dim3(ROWS / 64, D_SZ / 64), dim3(256), 0, stream>>>(outs, Wo, bo, y);
}